// Round 3
// baseline (1166.968 us; speedup 1.0000x reference)
//
#include <hip/hip_runtime.h>
#include <math.h>

#define NTOK 8192
#define DM 1024
#define NE 8
#define DF 4096
#define MAXTILES 72   // 256-row tiles: <=64 full + <=8 partial

typedef short  s16x8 __attribute__((ext_vector_type(8)));
typedef float  f32x4 __attribute__((ext_vector_type(4)));

// ---------------- workspace layout (bytes) ----------------
#define OFF_XN      0ull                       // 8192*1024*2        = 16777216
#define OFF_W1T     16777216ull                // 8*4096*1024*2      = 67108864
#define OFF_W2T     83886080ull                // 8*1024*4096*2      = 67108864
#define OFF_H       150994944ull               // 16384*4096*2       = 134217728
#define OFF_PROBS   285212672ull               // 8192*8*4           = 262144
#define OFF_TOPI    285474816ull               // 8192*2*4           = 65536
#define OFF_TOPP    285540352ull               // 8192*2*4           = 65536
#define OFF_ROWTOK  285605888ull               // 16384*4            = 65536
#define OFF_ROWP    285671424ull               // 16384*4            = 65536
#define OFF_COUNTS  285736960ull               // 8*4
#define OFF_CURSORS 285736992ull               // 8*4
#define OFF_NTILES  285737024ull               // 4 (+pad)
#define OFF_TILES   285737088ull               // 72*16
#define WS_NEEDED   285739264ull

__device__ __forceinline__ unsigned short f2bf(float f) {
  unsigned u = __builtin_bit_cast(unsigned, f);
  u += 0x7fffu + ((u >> 16) & 1u);
  return (unsigned short)(u >> 16);
}

__device__ __forceinline__ void gload_lds16(const void* g, void* l) {
  __builtin_amdgcn_global_load_lds(
      (const __attribute__((address_space(1))) void*)g,
      (__attribute__((address_space(3))) void*)l, 16, 0, 0);
}

// ---------------- init: zero expert counts ----------------
__global__ void init_kernel(unsigned* counts) {
  if (threadIdx.x < NE) counts[threadIdx.x] = 0u;
}

// ---------------- sentinel if ws too small ----------------
__global__ void sentinel_kernel(float* out, int n) {
  for (int i = blockIdx.x * 256 + threadIdx.x; i < n; i += 2048 * 256)
    out[i] = -12345.0f;
}

// ---------------- fused LayerNorm + router ----------------
__global__ __launch_bounds__(256) void ln_router_kernel(
    const float* __restrict__ x, const float* __restrict__ gamma,
    const float* __restrict__ beta, const float* __restrict__ rw,
    const float* __restrict__ rb, unsigned short* __restrict__ xnb,
    float* __restrict__ probs, int* __restrict__ topi,
    float* __restrict__ topp, unsigned* __restrict__ counts) {
  const int tok = blockIdx.x;
  const int t = threadIdx.x;
  const int lane = t & 63, wave = t >> 6;

  float4 xv = *(const float4*)(x + (size_t)tok * DM + t * 4);
  float s = xv.x + xv.y + xv.z + xv.w;
  float q = xv.x * xv.x + xv.y * xv.y + xv.z * xv.z + xv.w * xv.w;
  for (int o = 32; o > 0; o >>= 1) {
    s += __shfl_down(s, o);
    q += __shfl_down(q, o);
  }
  __shared__ float red[16];
  if (lane == 0) { red[wave] = s; red[8 + wave] = q; }
  __syncthreads();
  float tot  = red[0] + red[1] + red[2] + red[3];
  float totq = red[8] + red[9] + red[10] + red[11];
  float mu = tot * (1.0f / DM);
  float var = totq * (1.0f / DM) - mu * mu;
  float rstd = rsqrtf(var + 1e-5f);

  float4 g = *(const float4*)(gamma + t * 4);
  float4 b = *(const float4*)(beta + t * 4);
  float xn[4];
  xn[0] = (xv.x - mu) * rstd * g.x + b.x;
  xn[1] = (xv.y - mu) * rstd * g.y + b.y;
  xn[2] = (xv.z - mu) * rstd * g.z + b.z;
  xn[3] = (xv.w - mu) * rstd * g.w + b.w;
  ushort4 pk = { f2bf(xn[0]), f2bf(xn[1]), f2bf(xn[2]), f2bf(xn[3]) };
  *(ushort4*)(xnb + (size_t)tok * DM + t * 4) = pk;

  float a[8] = {0, 0, 0, 0, 0, 0, 0, 0};
  const float4* r4 = (const float4*)(rw + (size_t)t * 32);
#pragma unroll
  for (int j = 0; j < 4; ++j) {
    float4 lo = r4[j * 2], hi = r4[j * 2 + 1];
    a[0] += xn[j] * lo.x; a[1] += xn[j] * lo.y;
    a[2] += xn[j] * lo.z; a[3] += xn[j] * lo.w;
    a[4] += xn[j] * hi.x; a[5] += xn[j] * hi.y;
    a[6] += xn[j] * hi.z; a[7] += xn[j] * hi.w;
  }
#pragma unroll
  for (int e = 0; e < 8; ++e)
    for (int o = 32; o > 0; o >>= 1) a[e] += __shfl_down(a[e], o);
  __shared__ float lred[4][8];
  if (lane == 0) {
#pragma unroll
    for (int e = 0; e < 8; ++e) lred[wave][e] = a[e];
  }
  __syncthreads();
  if (t == 0) {
    float lg[8], mx = -1e30f;
#pragma unroll
    for (int e = 0; e < 8; ++e) {
      lg[e] = lred[0][e] + lred[1][e] + lred[2][e] + lred[3][e] + rb[e];
      mx = fmaxf(mx, lg[e]);
    }
    float ex[8], se = 0.f;
#pragma unroll
    for (int e = 0; e < 8; ++e) { ex[e] = expf(lg[e] - mx); se += ex[e]; }
    float inv = 1.f / se;
    float pr[8];
#pragma unroll
    for (int e = 0; e < 8; ++e) {
      pr[e] = ex[e] * inv;
      probs[tok * 8 + e] = pr[e];
    }
    int i0 = 0;
#pragma unroll
    for (int e = 1; e < 8; ++e) if (pr[e] > pr[i0]) i0 = e;
    int i1 = (i0 == 0) ? 1 : 0;
#pragma unroll
    for (int e = 0; e < 8; ++e)
      if (e != i0 && pr[e] > pr[i1]) i1 = e;
    float p0 = pr[i0], p1 = pr[i1], inv2 = 1.f / (p0 + p1);
    topi[tok * 2] = i0; topi[tok * 2 + 1] = i1;
    topp[tok * 2] = p0 * inv2; topp[tok * 2 + 1] = p1 * inv2;
    atomicAdd(&counts[i0], 1u);
    atomicAdd(&counts[i1], 1u);
  }
}

// ---------------- plan: offsets + 256-row tile descriptors ----------------
__global__ void plan_kernel(const unsigned* __restrict__ counts,
                            unsigned* __restrict__ cursors,
                            int4* __restrict__ tiles, int* __restrict__ ntiles) {
  if (threadIdx.x == 0 && blockIdx.x == 0) {
    unsigned o = 0; int nt = 0;
    for (int e = 0; e < NE; ++e) {
      cursors[e] = o;
      unsigned c = counts[e];
      for (unsigned st = 0; st < c; st += 256u) {
        unsigned nr = c - st; if (nr > 256u) nr = 256u;
        tiles[nt] = make_int4(e, (int)(o + st), (int)nr, 0);
        ++nt;
      }
      o += c;
    }
    *ntiles = nt;
  }
}

// ---------------- scatter tokens into expert row lists ----------------
__global__ __launch_bounds__(256) void scatter_kernel(
    const int* __restrict__ topi, const float* __restrict__ topp,
    unsigned* cursors, int* row_token, float* row_p) {
  int tok = blockIdx.x * 256 + threadIdx.x;
  if (tok >= NTOK) return;
#pragma unroll
  for (int k = 0; k < 2; ++k) {
    int e = topi[tok * 2 + k];
    unsigned pos = atomicAdd(&cursors[e], 1u);
    row_token[pos] = tok;
    row_p[pos] = topp[tok * 2 + k];
  }
}

// ---------------- aux loss ----------------
__global__ __launch_bounds__(256) void aux_kernel(const float* __restrict__ probs,
                                                  float* __restrict__ out_aux) {
  const int t = threadIdx.x;
  float a[8] = {0, 0, 0, 0, 0, 0, 0, 0};
  for (int tok = t; tok < NTOK; tok += 256) {
    const float4* p4 = (const float4*)(probs + (size_t)tok * 8);
    float4 lo = p4[0], hi = p4[1];
    a[0] += lo.x; a[1] += lo.y; a[2] += lo.z; a[3] += lo.w;
    a[4] += hi.x; a[5] += hi.y; a[6] += hi.z; a[7] += hi.w;
  }
  const int lane = t & 63, wave = t >> 6;
#pragma unroll
  for (int e = 0; e < 8; ++e)
    for (int o = 32; o > 0; o >>= 1) a[e] += __shfl_down(a[e], o);
  __shared__ float sh[4][8];
  if (lane == 0) {
#pragma unroll
    for (int e = 0; e < 8; ++e) sh[wave][e] = a[e];
  }
  __syncthreads();
  if (t == 0) {
    float aux = 0.f;
#pragma unroll
    for (int e = 0; e < 8; ++e) {
      float load = (sh[0][e] + sh[1][e] + sh[2][e] + sh[3][e]) * (1.f / NTOK);
      float d = load - 0.125f;
      aux += d * d;
    }
    out_aux[0] = aux;
  }
}

// ---------------- transpose + f32->bf16 cast: w[E][R][C] -> wt[E][C][R] ----------------
__global__ __launch_bounds__(256) void transpose_cast_kernel(
    const float* __restrict__ w, unsigned short* __restrict__ wt, int R, int C) {
  __shared__ float tile[32][33];
  const int e = blockIdx.z;
  const int c0 = blockIdx.x * 32, r0 = blockIdx.y * 32;
  const float* we = w + (size_t)e * R * C;
  unsigned short* wte = wt + (size_t)e * R * C;
  const int t = threadIdx.x;
  {
    int r = t >> 3, c = (t & 7) * 4;
    float4 v = *(const float4*)(we + (size_t)(r0 + r) * C + c0 + c);
    tile[r][c] = v.x; tile[r][c + 1] = v.y; tile[r][c + 2] = v.z; tile[r][c + 3] = v.w;
  }
  __syncthreads();
  {
    int c = t >> 3, r = (t & 7) * 4;
    ushort4 o;
    o.x = f2bf(tile[r][c]); o.y = f2bf(tile[r + 1][c]);
    o.z = f2bf(tile[r + 2][c]); o.w = f2bf(tile[r + 3][c]);
    *(ushort4*)(wte + (size_t)(c0 + c) * R + r0 + r) = o;
  }
}

// ---------------- residual copy ----------------
__global__ __launch_bounds__(256) void residual_kernel(const float4* __restrict__ x4,
                                                       float4* __restrict__ o4) {
  for (int i = blockIdx.x * 256 + threadIdx.x; i < (NTOK * DM / 4); i += 2048 * 256)
    o4[i] = x4[i];
}

// =====================================================================
// 256x256 8-phase GEMM (T1+T2+T3+T4+T5), 8 waves (2Mx4N), BK=64,
// 128 KB LDS double-buffer, counted vmcnt(8) (never 0 in main loop),
// raw s_barrier (no __syncthreads -> no vmcnt drain), XOR-swizzled LDS
// via pre-swizzled global source (rule #21), setprio around MFMA cluster.
// Per K-tile: stage(next, 8 loads) -> vmcnt(8) -> barrier -> 4 quadrant
// phases {12 ds_read_b128; sched_barrier; barrier; prio1; 16 MFMA; prio0;
// barrier; sched_barrier}.
// =====================================================================

__device__ __forceinline__ int xcd_swizzle(int nwg) {
  int wgid = blockIdx.y * gridDim.x + blockIdx.x;
  int q = nwg >> 3, r = nwg & 7;
  int xcd = wgid & 7, idx = wgid >> 3;
  return (xcd < r ? xcd * (q + 1) : r * (q + 1) + (xcd - r) * q) + idx;
}

#define GEMM_BODY(KDIM, A_ROW_PTR, B_PTR, B_STRIDE, EPILOGUE)                        \
  __shared__ unsigned short As[2][256 * 64];                                         \
  __shared__ unsigned short Bs[2][256 * 64];                                         \
  const int t = threadIdx.x;                                                         \
  const int lane = t & 63, wave = t >> 6;                                            \
  const int wr = wave >> 2, wc = wave & 3;                                           \
  const int swz = ((t & 7) ^ ((t >> 3) & 7)) * 8;                                    \
  const unsigned short* asrc[4];                                                     \
  const unsigned short* bsrc[4];                                                     \
  _Pragma("unroll")                                                                  \
  for (int c = 0; c < 4; ++c) {                                                      \
    int r = c * 64 + (t >> 3);                                                       \
    int rc = r < nrows ? r : (nrows - 1);                                            \
    asrc[c] = (A_ROW_PTR) + swz;                                                     \
    bsrc[c] = (B_PTR) + (size_t)(n0 + r) * (B_STRIDE) + swz;                         \
  }                                                                                  \
  f32x4 acc[8][4];                                                                   \
  _Pragma("unroll")                                                                  \
  for (int i = 0; i < 8; ++i)                                                        \
    _Pragma("unroll")                                                                \
    for (int j = 0; j < 4; ++j) acc[i][j] = (f32x4){0.f, 0.f, 0.f, 0.f};             \
  auto stage = [&](int buf, int k0) {                                                \
    _Pragma("unroll")                                                                \
    for (int c = 0; c < 4; ++c) {                                                    \
      gload_lds16(asrc[c] + k0, &As[buf][(c * 64 + wave * 8) * 64]);                 \
      gload_lds16(bsrc[c] + k0, &Bs[buf][(c * 64 + wave * 8) * 64]);                 \
    }                                                                                \
  };                                                                                 \
  stage(0, 0);                                                                       \
  const int NKT = (KDIM) / 64;                                                       \
  for (int kt = 0; kt < NKT; ++kt) {                                                 \
    const int buf = kt & 1;                                                          \
    if (kt + 1 < NKT) {                                                              \
      stage(buf ^ 1, (kt + 1) * 64);                                                 \
      asm volatile("s_waitcnt vmcnt(8)" ::: "memory");                               \
    } else {                                                                         \
      asm volatile("s_waitcnt vmcnt(0)" ::: "memory");                               \
    }                                                                                \
    __builtin_amdgcn_s_barrier();                                                    \
    const unsigned short* Ab = &As[buf][0];                                          \
    const unsigned short* Bb = &Bs[buf][0];                                          \
    _Pragma("unroll")                                                                \
    for (int ph = 0; ph < 4; ++ph) {                                                 \
      const int mh = ph >> 1, nh = ph & 1;                                           \
      s16x8 af[4][2], bfr[2][2];                                                     \
      _Pragma("unroll")                                                              \
      for (int ks = 0; ks < 2; ++ks) {                                               \
        const int slot = ((ks * 4 + (lane >> 4)) ^ (lane & 7)) * 8;                  \
        _Pragma("unroll")                                                            \
        for (int i = 0; i < 4; ++i)                                                  \
          af[i][ks] = *(const s16x8*)&Ab[(wr * 128 + (mh * 4 + i) * 16 +             \
                                          (lane & 15)) * 64 + slot];                 \
        _Pragma("unroll")                                                            \
        for (int j = 0; j < 2; ++j)                                                  \
          bfr[j][ks] = *(const s16x8*)&Bb[(wc * 64 + (nh * 2 + j) * 16 +             \
                                           (lane & 15)) * 64 + slot];                \
      }                                                                              \
      __builtin_amdgcn_sched_barrier(0);                                             \
      __builtin_amdgcn_s_barrier();                                                  \
      __builtin_amdgcn_s_setprio(1);                                                 \
      _Pragma("unroll")                                                              \
      for (int ks = 0; ks < 2; ++ks)                                                 \
        _Pragma("unroll")                                                            \
        for (int i = 0; i < 4; ++i)                                                  \
          _Pragma("unroll")                                                          \
          for (int j = 0; j < 2; ++j)                                                \
            acc[mh * 4 + i][nh * 2 + j] = __builtin_amdgcn_mfma_f32_16x16x32_bf16(   \
                af[i][ks], bfr[j][ks], acc[mh * 4 + i][nh * 2 + j], 0, 0, 0);        \
      __builtin_amdgcn_s_setprio(0);                                                 \
      __builtin_amdgcn_s_barrier();                                                  \
      __builtin_amdgcn_sched_barrier(0);                                             \
    }                                                                                \
  }                                                                                  \
  EPILOGUE

// ---------------- GEMM1: h = silu(xn[gather] @ w1 + b1), bf16 out ----------------
__global__ __launch_bounds__(512, 2) void gemm1_kernel(
    const unsigned short* __restrict__ xnb,   // [8192][1024]
    const unsigned short* __restrict__ w1t,   // [E][4096][1024]  ([n][k])
    const float* __restrict__ b1,             // [E][4096]
    const int* __restrict__ row_token,
    unsigned short* __restrict__ h,           // [16384][4096]
    const int4* __restrict__ tiles, const int* __restrict__ ntiles_p) {
  const int nwg = gridDim.x * gridDim.y;
  const int swzid = xcd_swizzle(nwg);
  const int tile = swzid / gridDim.x, bx = swzid % gridDim.x;
  if (tile >= *ntiles_p) return;
  const int4 td = tiles[tile];
  const int e = td.x, row_start = td.y, nrows = td.z;
  const int n0 = bx * 256;
  const unsigned short* Bw = w1t + (size_t)e * ((size_t)DF * DM);

  GEMM_BODY(DM,
            xnb + (size_t)row_token[row_start + rc] * DM,
            Bw, DM,
            {
              const float* b1e = b1 + e * DF;
              _Pragma("unroll")
              for (int mf = 0; mf < 8; ++mf) {
                int rbase = wr * 128 + mf * 16 + ((lane >> 4) << 2);
                _Pragma("unroll")
                for (int nf = 0; nf < 4; ++nf) {
                  int col = n0 + wc * 64 + nf * 16 + (lane & 15);
                  float bias = b1e[col];
                  _Pragma("unroll")
                  for (int r = 0; r < 4; ++r) {
                    int rl = rbase + r;
                    if (rl < nrows) {
                      float v = acc[mf][nf][r] + bias;
                      float sv = v / (1.f + __expf(-v));
                      h[(size_t)(row_start + rl) * DF + col] = f2bf(sv);
                    }
                  }
                }
              }
            })
}

// ---------------- GEMM2: out[token] += p * (h @ w2 + b2) ----------------
__global__ __launch_bounds__(512, 2) void gemm2_kernel(
    const unsigned short* __restrict__ h,     // [16384][4096]
    const unsigned short* __restrict__ w2t,   // [E][1024][4096]  ([n][k])
    const float* __restrict__ b2,             // [E][1024]
    const int* __restrict__ row_token, const float* __restrict__ row_p,
    const int4* __restrict__ tiles, const int* __restrict__ ntiles_p,
    float* __restrict__ out) {
  const int nwg = gridDim.x * gridDim.y;
  const int swzid = xcd_swizzle(nwg);
  const int tile = swzid / gridDim.x, bx = swzid % gridDim.x;
  if (tile >= *ntiles_p) return;
  const int4 td = tiles[tile];
  const int e = td.x, row_start = td.y, nrows = td.z;
  const int n0 = bx * 256;
  const unsigned short* Bw = w2t + (size_t)e * ((size_t)DM * DF);

  GEMM_BODY(DF,
            h + (size_t)(row_start + rc) * DF,
            Bw, DF,
            {
              const float* b2e = b2 + e * DM;
              _Pragma("unroll")
              for (int mf = 0; mf < 8; ++mf) {
                int rbase = wr * 128 + mf * 16 + ((lane >> 4) << 2);
                int tokr[4]; float prr[4];
                _Pragma("unroll")
                for (int r = 0; r < 4; ++r) {
                  int rl = rbase + r;
                  if (rl < nrows) {
                    tokr[r] = row_token[row_start + rl];
                    prr[r] = row_p[row_start + rl];
                  } else {
                    tokr[r] = -1; prr[r] = 0.f;
                  }
                }
                _Pragma("unroll")
                for (int nf = 0; nf < 4; ++nf) {
                  int col = n0 + wc * 64 + nf * 16 + (lane & 15);
                  float bias = b2e[col];
                  _Pragma("unroll")
                  for (int r = 0; r < 4; ++r) {
                    if (tokr[r] >= 0) {
                      float v = prr[r] * (acc[mf][nf][r] + bias);
                      atomicAdd(&out[(size_t)tokr[r] * DM + col], v);
                    }
                  }
                }
              }
            })
}

// ---------------- launch ----------------
extern "C" void kernel_launch(void* const* d_in, const int* in_sizes, int n_in,
                              void* d_out, int out_size, void* d_ws, size_t ws_size,
                              hipStream_t stream) {
  const float* x     = (const float*)d_in[0];
  const float* gamma = (const float*)d_in[1];
  const float* beta  = (const float*)d_in[2];
  const float* rw    = (const float*)d_in[3];
  const float* rb    = (const float*)d_in[4];
  const float* w1    = (const float*)d_in[5];
  const float* b1    = (const float*)d_in[6];
  const float* w2    = (const float*)d_in[7];
  const float* b2    = (const float*)d_in[8];
  float* out = (float*)d_out;
  char* ws = (char*)d_ws;

  if (ws_size < WS_NEEDED) {
    sentinel_kernel<<<2048, 256, 0, stream>>>(out, out_size);
    return;
  }

  unsigned short* xnb = (unsigned short*)(ws + OFF_XN);
  unsigned short* w1t = (unsigned short*)(ws + OFF_W1T);
  unsigned short* w2t = (unsigned short*)(ws + OFF_W2T);
  unsigned short* h   = (unsigned short*)(ws + OFF_H);
  float* probs        = (float*)(ws + OFF_PROBS);
  int* topi           = (int*)(ws + OFF_TOPI);
  float* topp         = (float*)(ws + OFF_TOPP);
  int* row_token      = (int*)(ws + OFF_ROWTOK);
  float* row_p        = (float*)(ws + OFF_ROWP);
  unsigned* counts    = (unsigned*)(ws + OFF_COUNTS);
  unsigned* cursors   = (unsigned*)(ws + OFF_CURSORS);
  int* ntiles         = (int*)(ws + OFF_NTILES);
  int4* tiles         = (int4*)(ws + OFF_TILES);

  init_kernel<<<1, 64, 0, stream>>>(counts);
  ln_router_kernel<<<NTOK, 256, 0, stream>>>(x, gamma, beta, rw, rb, xnb, probs,
                                             topi, topp, counts);
  plan_kernel<<<1, 1, 0, stream>>>(counts, cursors, tiles, ntiles);
  scatter_kernel<<<NTOK / 256, 256, 0, stream>>>(topi, topp, cursors, row_token, row_p);
  aux_kernel<<<1, 256, 0, stream>>>(probs, out + (size_t)NTOK * DM);
  transpose_cast_kernel<<<dim3(DF / 32, DM / 32, NE), 256, 0, stream>>>(w1, w1t, DM, DF);
  transpose_cast_kernel<<<dim3(DM / 32, DF / 32, NE), 256, 0, stream>>>(w2, w2t, DF, DM);
  residual_kernel<<<2048, 256, 0, stream>>>((const float4*)x, (float4*)out);
  gemm1_kernel<<<dim3(DF / 256, MAXTILES), 512, 0, stream>>>(xnb, w1t, b1, row_token,
                                                             h, tiles, ntiles);
  gemm2_kernel<<<dim3(DM / 256, MAXTILES), 512, 0, stream>>>(h, w2t, b2, row_token,
                                                             row_p, tiles, ntiles, out);
}

// Round 4
// 1054.984 us; speedup vs baseline: 1.1061x; 1.1061x over previous
//
#include <hip/hip_runtime.h>
#include <math.h>

#define NTOK 8192
#define DM 1024
#define NE 8
#define DF 4096
#define MAXTILES 72   // 256-row tiles: <=64 full + <=8 partial

typedef short  s16x8 __attribute__((ext_vector_type(8)));
typedef float  f32x4 __attribute__((ext_vector_type(4)));

// ---------------- workspace layout (bytes) ----------------
#define OFF_XN      0ull                       // 8192*1024*2        = 16777216
#define OFF_W1T     16777216ull                // 8*4096*1024*2      = 67108864
#define OFF_W2T     83886080ull                // 8*1024*4096*2      = 67108864
#define OFF_H       150994944ull               // 16384*4096*2       = 134217728
#define OFF_PROBS   285212672ull               // 8192*8*4           = 262144
#define OFF_TOPI    285474816ull               // 8192*2*4           = 65536
#define OFF_TOPP    285540352ull               // 8192*2*4           = 65536
#define OFF_ROWTOK  285605888ull               // 16384*4            = 65536
#define OFF_ROWP    285671424ull               // 16384*4            = 65536
#define OFF_COUNTS  285736960ull               // 8*4
#define OFF_CURSORS 285736992ull               // 8*4
#define OFF_NTILES  285737024ull               // 4 (+pad)
#define OFF_TILES   285737088ull               // 72*16
#define WS_NEEDED   285739264ull

__device__ __forceinline__ unsigned short f2bf(float f) {
  unsigned u = __builtin_bit_cast(unsigned, f);
  u += 0x7fffu + ((u >> 16) & 1u);
  return (unsigned short)(u >> 16);
}

__device__ __forceinline__ void gload_lds16(const void* g, void* l) {
  __builtin_amdgcn_global_load_lds(
      (const __attribute__((address_space(1))) void*)g,
      (__attribute__((address_space(3))) void*)l, 16, 0, 0);
}

// ---------------- init: zero expert counts ----------------
__global__ void init_kernel(unsigned* counts) {
  if (threadIdx.x < NE) counts[threadIdx.x] = 0u;
}

// ---------------- sentinel if ws too small ----------------
__global__ void sentinel_kernel(float* out, int n) {
  for (int i = blockIdx.x * 256 + threadIdx.x; i < n; i += 2048 * 256)
    out[i] = -12345.0f;
}

// ---------------- fused LayerNorm + router + residual-init ----------------
__global__ __launch_bounds__(256) void ln_router_kernel(
    const float* __restrict__ x, const float* __restrict__ gamma,
    const float* __restrict__ beta, const float* __restrict__ rw,
    const float* __restrict__ rb, unsigned short* __restrict__ xnb,
    float* __restrict__ probs, int* __restrict__ topi,
    float* __restrict__ topp, unsigned* __restrict__ counts,
    float* __restrict__ out) {
  const int tok = blockIdx.x;
  const int t = threadIdx.x;
  const int lane = t & 63, wave = t >> 6;

  float4 xv = *(const float4*)(x + (size_t)tok * DM + t * 4);
  // residual init: out starts as x (gemm2 atomically accumulates on top)
  *(float4*)(out + (size_t)tok * DM + t * 4) = xv;

  float s = xv.x + xv.y + xv.z + xv.w;
  float q = xv.x * xv.x + xv.y * xv.y + xv.z * xv.z + xv.w * xv.w;
  for (int o = 32; o > 0; o >>= 1) {
    s += __shfl_down(s, o);
    q += __shfl_down(q, o);
  }
  __shared__ float red[16];
  if (lane == 0) { red[wave] = s; red[8 + wave] = q; }
  __syncthreads();
  float tot  = red[0] + red[1] + red[2] + red[3];
  float totq = red[8] + red[9] + red[10] + red[11];
  float mu = tot * (1.0f / DM);
  float var = totq * (1.0f / DM) - mu * mu;
  float rstd = rsqrtf(var + 1e-5f);

  float4 g = *(const float4*)(gamma + t * 4);
  float4 b = *(const float4*)(beta + t * 4);
  float xn[4];
  xn[0] = (xv.x - mu) * rstd * g.x + b.x;
  xn[1] = (xv.y - mu) * rstd * g.y + b.y;
  xn[2] = (xv.z - mu) * rstd * g.z + b.z;
  xn[3] = (xv.w - mu) * rstd * g.w + b.w;
  ushort4 pk = { f2bf(xn[0]), f2bf(xn[1]), f2bf(xn[2]), f2bf(xn[3]) };
  *(ushort4*)(xnb + (size_t)tok * DM + t * 4) = pk;

  float a[8] = {0, 0, 0, 0, 0, 0, 0, 0};
  const float4* r4 = (const float4*)(rw + (size_t)t * 32);
#pragma unroll
  for (int j = 0; j < 4; ++j) {
    float4 lo = r4[j * 2], hi = r4[j * 2 + 1];
    a[0] += xn[j] * lo.x; a[1] += xn[j] * lo.y;
    a[2] += xn[j] * lo.z; a[3] += xn[j] * lo.w;
    a[4] += xn[j] * hi.x; a[5] += xn[j] * hi.y;
    a[6] += xn[j] * hi.z; a[7] += xn[j] * hi.w;
  }
#pragma unroll
  for (int e = 0; e < 8; ++e)
    for (int o = 32; o > 0; o >>= 1) a[e] += __shfl_down(a[e], o);
  __shared__ float lred[4][8];
  if (lane == 0) {
#pragma unroll
    for (int e = 0; e < 8; ++e) lred[wave][e] = a[e];
  }
  __syncthreads();
  if (t == 0) {
    float lg[8], mx = -1e30f;
#pragma unroll
    for (int e = 0; e < 8; ++e) {
      lg[e] = lred[0][e] + lred[1][e] + lred[2][e] + lred[3][e] + rb[e];
      mx = fmaxf(mx, lg[e]);
    }
    float ex[8], se = 0.f;
#pragma unroll
    for (int e = 0; e < 8; ++e) { ex[e] = expf(lg[e] - mx); se += ex[e]; }
    float inv = 1.f / se;
    float pr[8];
#pragma unroll
    for (int e = 0; e < 8; ++e) {
      pr[e] = ex[e] * inv;
      probs[tok * 8 + e] = pr[e];
    }
    int i0 = 0;
#pragma unroll
    for (int e = 1; e < 8; ++e) if (pr[e] > pr[i0]) i0 = e;
    int i1 = (i0 == 0) ? 1 : 0;
#pragma unroll
    for (int e = 0; e < 8; ++e)
      if (e != i0 && pr[e] > pr[i1]) i1 = e;
    float p0 = pr[i0], p1 = pr[i1], inv2 = 1.f / (p0 + p1);
    topi[tok * 2] = i0; topi[tok * 2 + 1] = i1;
    topp[tok * 2] = p0 * inv2; topp[tok * 2 + 1] = p1 * inv2;
    atomicAdd(&counts[i0], 1u);
    atomicAdd(&counts[i1], 1u);
  }
}

// ---------------- plan: offsets + 256-row tile descriptors ----------------
__global__ void plan_kernel(const unsigned* __restrict__ counts,
                            unsigned* __restrict__ cursors,
                            int4* __restrict__ tiles, int* __restrict__ ntiles) {
  if (threadIdx.x == 0 && blockIdx.x == 0) {
    unsigned o = 0; int nt = 0;
    for (int e = 0; e < NE; ++e) {
      cursors[e] = o;
      unsigned c = counts[e];
      for (unsigned st = 0; st < c; st += 256u) {
        unsigned nr = c - st; if (nr > 256u) nr = 256u;
        tiles[nt] = make_int4(e, (int)(o + st), (int)nr, 0);
        ++nt;
      }
      o += c;
    }
    *ntiles = nt;
  }
}

// ---------------- scatter tokens into expert row lists ----------------
__global__ __launch_bounds__(256) void scatter_kernel(
    const int* __restrict__ topi, const float* __restrict__ topp,
    unsigned* cursors, int* row_token, float* row_p) {
  int tok = blockIdx.x * 256 + threadIdx.x;
  if (tok >= NTOK) return;
#pragma unroll
  for (int k = 0; k < 2; ++k) {
    int e = topi[tok * 2 + k];
    unsigned pos = atomicAdd(&cursors[e], 1u);
    row_token[pos] = tok;
    row_p[pos] = topp[tok * 2 + k];
  }
}

// ---------------- aux loss ----------------
__global__ __launch_bounds__(256) void aux_kernel(const float* __restrict__ probs,
                                                  float* __restrict__ out_aux) {
  const int t = threadIdx.x;
  float a[8] = {0, 0, 0, 0, 0, 0, 0, 0};
  for (int tok = t; tok < NTOK; tok += 256) {
    const float4* p4 = (const float4*)(probs + (size_t)tok * 8);
    float4 lo = p4[0], hi = p4[1];
    a[0] += lo.x; a[1] += lo.y; a[2] += lo.z; a[3] += lo.w;
    a[4] += hi.x; a[5] += hi.y; a[6] += hi.z; a[7] += hi.w;
  }
  const int lane = t & 63, wave = t >> 6;
#pragma unroll
  for (int e = 0; e < 8; ++e)
    for (int o = 32; o > 0; o >>= 1) a[e] += __shfl_down(a[e], o);
  __shared__ float sh[4][8];
  if (lane == 0) {
#pragma unroll
    for (int e = 0; e < 8; ++e) sh[wave][e] = a[e];
  }
  __syncthreads();
  if (t == 0) {
    float aux = 0.f;
#pragma unroll
    for (int e = 0; e < 8; ++e) {
      float load = (sh[0][e] + sh[1][e] + sh[2][e] + sh[3][e]) * (1.f / NTOK);
      float d = load - 0.125f;
      aux += d * d;
    }
    out_aux[0] = aux;
  }
}

// ---------------- transpose + f32->bf16 cast: w[E][R][C] -> wt[E][C][R] ----------------
__global__ __launch_bounds__(256) void transpose_cast_kernel(
    const float* __restrict__ w, unsigned short* __restrict__ wt, int R, int C) {
  __shared__ float tile[32][33];
  const int e = blockIdx.z;
  const int c0 = blockIdx.x * 32, r0 = blockIdx.y * 32;
  const float* we = w + (size_t)e * R * C;
  unsigned short* wte = wt + (size_t)e * R * C;
  const int t = threadIdx.x;
  {
    int r = t >> 3, c = (t & 7) * 4;
    float4 v = *(const float4*)(we + (size_t)(r0 + r) * C + c0 + c);
    tile[r][c] = v.x; tile[r][c + 1] = v.y; tile[r][c + 2] = v.z; tile[r][c + 3] = v.w;
  }
  __syncthreads();
  {
    int c = t >> 3, r = (t & 7) * 4;
    ushort4 o;
    o.x = f2bf(tile[r][c]); o.y = f2bf(tile[r + 1][c]);
    o.z = f2bf(tile[r + 2][c]); o.w = f2bf(tile[r + 3][c]);
    *(ushort4*)(wte + (size_t)(c0 + c) * R + r0 + r) = o;
  }
}

// =====================================================================
// 256x256 GEMM, 8 waves (2Mx4N), BK=64, 128 KB LDS double-buffer.
// - Work-item grid-stride with XCD-chunked item map (256 blocks exactly;
//   dead items distribute evenly; a tile's column-blocks stay on one XCD).
// - Per K-tile: stage-all-8 -> vmcnt(8) (never 0 in-loop) -> s_barrier ->
//   4 zigzag quadrant phases (0,0)(0,1)(1,1)(1,0) with register reuse:
//   ds_read_b128 per phase = 12,4,8,0 (24/K-tile vs 48 naive).
// - XOR-swizzled LDS via pre-swizzled global source (rule #21).
// - setprio(1) around each 16-MFMA cluster (T5).
// =====================================================================

#define SLOT(ks) (((ks) * 4 + (lane >> 4)) ^ (lane & 7)) * 8

#define LOAD_A(MH)                                                                   \
  _Pragma("unroll")                                                                  \
  for (int ks = 0; ks < 2; ++ks) {                                                   \
    const int slot = SLOT(ks);                                                       \
    _Pragma("unroll")                                                                \
    for (int i = 0; i < 4; ++i)                                                      \
      af[i][ks] = *(const s16x8*)&Ab[(wr * 128 + ((MH) * 4 + i) * 16 +               \
                                      (lane & 15)) * 64 + slot];                     \
  }

#define LOAD_B(NH, BF)                                                               \
  _Pragma("unroll")                                                                  \
  for (int ks = 0; ks < 2; ++ks) {                                                   \
    const int slot = SLOT(ks);                                                       \
    _Pragma("unroll")                                                                \
    for (int j = 0; j < 2; ++j)                                                      \
      BF[j][ks] = *(const s16x8*)&Bb[(wc * 64 + ((NH) * 2 + j) * 16 +                \
                                      (lane & 15)) * 64 + slot];                     \
  }

#define MFMA_QUAD(MH, NH, BF)                                                        \
  __builtin_amdgcn_s_setprio(1);                                                     \
  _Pragma("unroll")                                                                  \
  for (int ks = 0; ks < 2; ++ks)                                                     \
    _Pragma("unroll")                                                                \
    for (int i = 0; i < 4; ++i)                                                      \
      _Pragma("unroll")                                                              \
      for (int j = 0; j < 2; ++j)                                                    \
        acc[(MH) * 4 + i][(NH) * 2 + j] = __builtin_amdgcn_mfma_f32_16x16x32_bf16(   \
            af[i][ks], BF[j][ks], acc[(MH) * 4 + i][(NH) * 2 + j], 0, 0, 0);         \
  __builtin_amdgcn_s_setprio(0);

#define SBAR __builtin_amdgcn_s_barrier()
#define SCHB __builtin_amdgcn_sched_barrier(0)

#define GEMM_LOOP_BODY(NBXLOG, KDIM, AROW_PTR, BBASE, BSTRIDE, EPILOGUE)             \
  __shared__ unsigned short As[2][256 * 64];                                         \
  __shared__ unsigned short Bs[2][256 * 64];                                         \
  const int t = threadIdx.x;                                                         \
  const int lane = t & 63, wave = t >> 6;                                            \
  const int wr = wave >> 2, wc = wave & 3;                                           \
  const int swz = ((t & 7) ^ ((t >> 3) & 7)) * 8;                                    \
  const int nItems = (*ntiles_p) << (NBXLOG);                                        \
  const int cs = (nItems + 7) >> 3;                                                  \
  const int xcd = blockIdx.x & 7, lnx = blockIdx.x >> 3;                             \
  const int wend = ((xcd + 1) * cs < nItems) ? (xcd + 1) * cs : nItems;              \
  const int wstep = (int)(gridDim.x >> 3);                                           \
  for (int w = xcd * cs + lnx; w < wend; w += wstep) {                               \
    const int4 td = tiles[w >> (NBXLOG)];                                            \
    const int e = td.x, row_start = td.y, nrows = td.z;                              \
    const int n0 = (w & ((1 << (NBXLOG)) - 1)) * 256;                                \
    const unsigned short* asrc[4];                                                   \
    const unsigned short* bsrc[4];                                                   \
    _Pragma("unroll")                                                                \
    for (int c = 0; c < 4; ++c) {                                                    \
      int r = c * 64 + (t >> 3);                                                     \
      int rc = r < nrows ? r : (nrows - 1);                                          \
      asrc[c] = (AROW_PTR) + swz;                                                    \
      bsrc[c] = (BBASE) + (size_t)(n0 + r) * (BSTRIDE) + swz;                        \
    }                                                                                \
    f32x4 acc[8][4];                                                                 \
    _Pragma("unroll")                                                                \
    for (int i = 0; i < 8; ++i)                                                      \
      _Pragma("unroll")                                                              \
      for (int j = 0; j < 4; ++j) acc[i][j] = (f32x4){0.f, 0.f, 0.f, 0.f};           \
    auto stage = [&](int buf, int k0) {                                              \
      _Pragma("unroll")                                                              \
      for (int c = 0; c < 4; ++c) {                                                  \
        gload_lds16(asrc[c] + k0, &As[buf][(c * 64 + wave * 8) * 64]);               \
        gload_lds16(bsrc[c] + k0, &Bs[buf][(c * 64 + wave * 8) * 64]);               \
      }                                                                              \
    };                                                                               \
    stage(0, 0);                                                                     \
    const int NKT = (KDIM) / 64;                                                     \
    for (int kt = 0; kt < NKT; ++kt) {                                               \
      const int buf = kt & 1;                                                        \
      if (kt + 1 < NKT) {                                                            \
        stage(buf ^ 1, (kt + 1) * 64);                                               \
        asm volatile("s_waitcnt vmcnt(8)" ::: "memory");                             \
      } else {                                                                       \
        asm volatile("s_waitcnt vmcnt(0)" ::: "memory");                             \
      }                                                                              \
      SBAR;                                                                          \
      const unsigned short* Ab = &As[buf][0];                                        \
      const unsigned short* Bb = &Bs[buf][0];                                        \
      s16x8 af[4][2], bf0[2][2], bf1[2][2];                                          \
      /* phase 0: (mh0,nh0) */                                                       \
      LOAD_A(0) LOAD_B(0, bf0) SCHB; SBAR;                                           \
      MFMA_QUAD(0, 0, bf0) SBAR; SCHB;                                               \
      /* phase 1: (mh0,nh1) */                                                       \
      LOAD_B(1, bf1) SCHB; SBAR;                                                     \
      MFMA_QUAD(0, 1, bf1) SBAR; SCHB;                                               \
      /* phase 2: (mh1,nh1) */                                                       \
      LOAD_A(1) SCHB; SBAR;                                                          \
      MFMA_QUAD(1, 1, bf1) SBAR; SCHB;                                               \
      /* phase 3: (mh1,nh0), no new loads */                                         \
      MFMA_QUAD(1, 0, bf0) SBAR; SCHB;                                               \
    }                                                                                \
    EPILOGUE                                                                         \
  }

// ---------------- GEMM1: h = silu(xn[gather] @ w1 + b1), bf16 out ----------------
__global__ __launch_bounds__(512, 2) void gemm1_kernel(
    const unsigned short* __restrict__ xnb,   // [8192][1024]
    const unsigned short* __restrict__ w1t,   // [E][4096][1024]  ([n][k])
    const float* __restrict__ b1,             // [E][4096]
    const int* __restrict__ row_token,
    unsigned short* __restrict__ h,           // [16384][4096]
    const int4* __restrict__ tiles, const int* __restrict__ ntiles_p) {
  GEMM_LOOP_BODY(4, DM,
                 xnb + (size_t)row_token[row_start + rc] * DM,
                 w1t + (size_t)e * ((size_t)DF * DM), DM,
                 {
                   const float* b1e = b1 + e * DF;
                   _Pragma("unroll")
                   for (int mf = 0; mf < 8; ++mf) {
                     int rbase = wr * 128 + mf * 16 + ((lane >> 4) << 2);
                     _Pragma("unroll")
                     for (int nf = 0; nf < 4; ++nf) {
                       int col = n0 + wc * 64 + nf * 16 + (lane & 15);
                       float bias = b1e[col];
                       _Pragma("unroll")
                       for (int r = 0; r < 4; ++r) {
                         int rl = rbase + r;
                         if (rl < nrows) {
                           float v = acc[mf][nf][r] + bias;
                           float sv = v / (1.f + __expf(-v));
                           h[(size_t)(row_start + rl) * DF + col] = f2bf(sv);
                         }
                       }
                     }
                   }
                 })
}

// ---------------- GEMM2: out[token] += p * (h @ w2 + b2) ----------------
__global__ __launch_bounds__(512, 2) void gemm2_kernel(
    const unsigned short* __restrict__ h,     // [16384][4096]
    const unsigned short* __restrict__ w2t,   // [E][1024][4096]  ([n][k])
    const float* __restrict__ b2,             // [E][1024]
    const int* __restrict__ row_token, const float* __restrict__ row_p,
    const int4* __restrict__ tiles, const int* __restrict__ ntiles_p,
    float* __restrict__ out) {
  GEMM_LOOP_BODY(2, DF,
                 h + (size_t)(row_start + rc) * DF,
                 w2t + (size_t)e * ((size_t)DM * DF), DF,
                 {
                   const float* b2e = b2 + e * DM;
                   _Pragma("unroll")
                   for (int mf = 0; mf < 8; ++mf) {
                     int rbase = wr * 128 + mf * 16 + ((lane >> 4) << 2);
                     int tokr[4]; float prr[4];
                     _Pragma("unroll")
                     for (int r = 0; r < 4; ++r) {
                       int rl = rbase + r;
                       if (rl < nrows) {
                         tokr[r] = row_token[row_start + rl];
                         prr[r] = row_p[row_start + rl];
                       } else {
                         tokr[r] = -1; prr[r] = 0.f;
                       }
                     }
                     _Pragma("unroll")
                     for (int nf = 0; nf < 4; ++nf) {
                       int col = n0 + wc * 64 + nf * 16 + (lane & 15);
                       float bias = b2e[col];
                       _Pragma("unroll")
                       for (int r = 0; r < 4; ++r) {
                         if (tokr[r] >= 0) {
                           float v = prr[r] * (acc[mf][nf][r] + bias);
                           atomicAdd(&out[(size_t)tokr[r] * DM + col], v);
                         }
                       }
                     }
                   }
                 })
}

// ---------------- launch ----------------
extern "C" void kernel_launch(void* const* d_in, const int* in_sizes, int n_in,
                              void* d_out, int out_size, void* d_ws, size_t ws_size,
                              hipStream_t stream) {
  const float* x     = (const float*)d_in[0];
  const float* gamma = (const float*)d_in[1];
  const float* beta  = (const float*)d_in[2];
  const float* rw    = (const float*)d_in[3];
  const float* rb    = (const float*)d_in[4];
  const float* w1    = (const float*)d_in[5];
  const float* b1    = (const float*)d_in[6];
  const float* w2    = (const float*)d_in[7];
  const float* b2    = (const float*)d_in[8];
  float* out = (float*)d_out;
  char* ws = (char*)d_ws;

  if (ws_size < WS_NEEDED) {
    sentinel_kernel<<<2048, 256, 0, stream>>>(out, out_size);
    return;
  }

  unsigned short* xnb = (unsigned short*)(ws + OFF_XN);
  unsigned short* w1t = (unsigned short*)(ws + OFF_W1T);
  unsigned short* w2t = (unsigned short*)(ws + OFF_W2T);
  unsigned short* h   = (unsigned short*)(ws + OFF_H);
  float* probs        = (float*)(ws + OFF_PROBS);
  int* topi           = (int*)(ws + OFF_TOPI);
  float* topp         = (float*)(ws + OFF_TOPP);
  int* row_token      = (int*)(ws + OFF_ROWTOK);
  float* row_p        = (float*)(ws + OFF_ROWP);
  unsigned* counts    = (unsigned*)(ws + OFF_COUNTS);
  unsigned* cursors   = (unsigned*)(ws + OFF_CURSORS);
  int* ntiles         = (int*)(ws + OFF_NTILES);
  int4* tiles         = (int4*)(ws + OFF_TILES);

  init_kernel<<<1, 64, 0, stream>>>(counts);
  ln_router_kernel<<<NTOK, 256, 0, stream>>>(x, gamma, beta, rw, rb, xnb, probs,
                                             topi, topp, counts, out);
  plan_kernel<<<1, 1, 0, stream>>>(counts, cursors, tiles, ntiles);
  scatter_kernel<<<NTOK / 256, 256, 0, stream>>>(topi, topp, cursors, row_token, row_p);
  aux_kernel<<<1, 256, 0, stream>>>(probs, out + (size_t)NTOK * DM);
  transpose_cast_kernel<<<dim3(DF / 32, DM / 32, NE), 256, 0, stream>>>(w1, w1t, DM, DF);
  transpose_cast_kernel<<<dim3(DM / 32, DF / 32, NE), 256, 0, stream>>>(w2, w2t, DF, DM);
  gemm1_kernel<<<256, 512, 0, stream>>>(xnb, w1t, b1, row_token, h, tiles, ntiles);
  gemm2_kernel<<<256, 512, 0, stream>>>(h, w2t, b2, row_token, row_p, tiles, ntiles, out);
}

// Round 5
// 851.474 us; speedup vs baseline: 1.3705x; 1.2390x over previous
//
#include <hip/hip_runtime.h>
#include <math.h>

#define NTOK 8192
#define DM 1024
#define NE 8
#define DF 4096
#define MAXTILES 136   // 128-row tiles: <=128 full + <=8 partial

typedef short  s16x8 __attribute__((ext_vector_type(8)));
typedef float  f32x4 __attribute__((ext_vector_type(4)));

// ---------------- workspace layout (bytes) ----------------
#define OFF_XN      0ull                       // 8192*1024*2        = 16777216
#define OFF_W1T     16777216ull                // 8*4096*1024*2      = 67108864  (y overlays after gemm1)
#define OFF_W2T     83886080ull                // 8*1024*4096*2      = 67108864
#define OFF_H       150994944ull               // 16384*4096*2       = 134217728
#define OFF_PROBS   285212672ull               // 8192*8*4           = 262144
#define OFF_TOPI    285474816ull               // 8192*2*4           = 65536 (becomes asn rows)
#define OFF_TOPP    285540352ull               // 8192*2*4           = 65536
#define OFF_ROWTOK  285605888ull               // 16384*4            = 65536
#define OFF_ROWP    285671424ull               // 16384*4            = 65536
#define OFF_COUNTS  285736960ull               // 8*4
#define OFF_CURSORS 285736992ull               // 8*4
#define OFF_NTILES  285737024ull               // 4 (+pad)
#define OFF_TILES   285737088ull               // 136*16 = 2176
#define WS_NEEDED   285739264ull

__device__ __forceinline__ unsigned short f2bf(float f) {
  unsigned u = __builtin_bit_cast(unsigned, f);
  u += 0x7fffu + ((u >> 16) & 1u);
  return (unsigned short)(u >> 16);
}
__device__ __forceinline__ float bf2f(unsigned short s) {
  unsigned u = ((unsigned)s) << 16;
  return __builtin_bit_cast(float, u);
}

__device__ __forceinline__ void gload_lds16(const void* g, void* l) {
  __builtin_amdgcn_global_load_lds(
      (const __attribute__((address_space(1))) void*)g,
      (__attribute__((address_space(3))) void*)l, 16, 0, 0);
}

// ---------------- init: zero expert counts ----------------
__global__ void init_kernel(unsigned* counts) {
  if (threadIdx.x < NE) counts[threadIdx.x] = 0u;
}

// ---------------- sentinel if ws too small ----------------
__global__ void sentinel_kernel(float* out, int n) {
  for (int i = blockIdx.x * 256 + threadIdx.x; i < n; i += 2048 * 256)
    out[i] = -12345.0f;
}

// ---------------- fused LayerNorm + router ----------------
__global__ __launch_bounds__(256) void ln_router_kernel(
    const float* __restrict__ x, const float* __restrict__ gamma,
    const float* __restrict__ beta, const float* __restrict__ rw,
    const float* __restrict__ rb, unsigned short* __restrict__ xnb,
    float* __restrict__ probs, int* __restrict__ topi,
    float* __restrict__ topp, unsigned* __restrict__ counts) {
  const int tok = blockIdx.x;
  const int t = threadIdx.x;
  const int lane = t & 63, wave = t >> 6;

  float4 xv = *(const float4*)(x + (size_t)tok * DM + t * 4);
  float s = xv.x + xv.y + xv.z + xv.w;
  float q = xv.x * xv.x + xv.y * xv.y + xv.z * xv.z + xv.w * xv.w;
  for (int o = 32; o > 0; o >>= 1) {
    s += __shfl_down(s, o);
    q += __shfl_down(q, o);
  }
  __shared__ float red[16];
  if (lane == 0) { red[wave] = s; red[8 + wave] = q; }
  __syncthreads();
  float tot  = red[0] + red[1] + red[2] + red[3];
  float totq = red[8] + red[9] + red[10] + red[11];
  float mu = tot * (1.0f / DM);
  float var = totq * (1.0f / DM) - mu * mu;
  float rstd = rsqrtf(var + 1e-5f);

  float4 g = *(const float4*)(gamma + t * 4);
  float4 b = *(const float4*)(beta + t * 4);
  float xn[4];
  xn[0] = (xv.x - mu) * rstd * g.x + b.x;
  xn[1] = (xv.y - mu) * rstd * g.y + b.y;
  xn[2] = (xv.z - mu) * rstd * g.z + b.z;
  xn[3] = (xv.w - mu) * rstd * g.w + b.w;
  ushort4 pk = { f2bf(xn[0]), f2bf(xn[1]), f2bf(xn[2]), f2bf(xn[3]) };
  *(ushort4*)(xnb + (size_t)tok * DM + t * 4) = pk;

  float a[8] = {0, 0, 0, 0, 0, 0, 0, 0};
  const float4* r4 = (const float4*)(rw + (size_t)t * 32);
#pragma unroll
  for (int j = 0; j < 4; ++j) {
    float4 lo = r4[j * 2], hi = r4[j * 2 + 1];
    a[0] += xn[j] * lo.x; a[1] += xn[j] * lo.y;
    a[2] += xn[j] * lo.z; a[3] += xn[j] * lo.w;
    a[4] += xn[j] * hi.x; a[5] += xn[j] * hi.y;
    a[6] += xn[j] * hi.z; a[7] += xn[j] * hi.w;
  }
#pragma unroll
  for (int e = 0; e < 8; ++e)
    for (int o = 32; o > 0; o >>= 1) a[e] += __shfl_down(a[e], o);
  __shared__ float lred[4][8];
  if (lane == 0) {
#pragma unroll
    for (int e = 0; e < 8; ++e) lred[wave][e] = a[e];
  }
  __syncthreads();
  if (t == 0) {
    float lg[8], mx = -1e30f;
#pragma unroll
    for (int e = 0; e < 8; ++e) {
      lg[e] = lred[0][e] + lred[1][e] + lred[2][e] + lred[3][e] + rb[e];
      mx = fmaxf(mx, lg[e]);
    }
    float ex[8], se = 0.f;
#pragma unroll
    for (int e = 0; e < 8; ++e) { ex[e] = expf(lg[e] - mx); se += ex[e]; }
    float inv = 1.f / se;
    float pr[8];
#pragma unroll
    for (int e = 0; e < 8; ++e) {
      pr[e] = ex[e] * inv;
      probs[tok * 8 + e] = pr[e];
    }
    int i0 = 0;
#pragma unroll
    for (int e = 1; e < 8; ++e) if (pr[e] > pr[i0]) i0 = e;
    int i1 = (i0 == 0) ? 1 : 0;
#pragma unroll
    for (int e = 0; e < 8; ++e)
      if (e != i0 && pr[e] > pr[i1]) i1 = e;
    float p0 = pr[i0], p1 = pr[i1], inv2 = 1.f / (p0 + p1);
    topi[tok * 2] = i0; topi[tok * 2 + 1] = i1;
    topp[tok * 2] = p0 * inv2; topp[tok * 2 + 1] = p1 * inv2;
    atomicAdd(&counts[i0], 1u);
    atomicAdd(&counts[i1], 1u);
  }
}

// ---------------- plan: offsets + 128-row tile descriptors ----------------
__global__ void plan_kernel(const unsigned* __restrict__ counts,
                            unsigned* __restrict__ cursors,
                            int4* __restrict__ tiles, int* __restrict__ ntiles) {
  if (threadIdx.x == 0 && blockIdx.x == 0) {
    unsigned o = 0; int nt = 0;
    for (int e = 0; e < NE; ++e) {
      cursors[e] = o;
      unsigned c = counts[e];
      for (unsigned st = 0; st < c; st += 128u) {
        unsigned nr = c - st; if (nr > 128u) nr = 128u;
        tiles[nt] = make_int4(e, (int)(o + st), (int)nr, 0);
        ++nt;
      }
      o += c;
    }
    *ntiles = nt;
  }
}

// ------- scatter: expert row lists + per-token assignment rows (into topi) -------
__global__ __launch_bounds__(256) void scatter_kernel(
    int* __restrict__ topi, const float* __restrict__ topp,
    unsigned* cursors, int* row_token, float* row_p) {
  int tok = blockIdx.x * 256 + threadIdx.x;
  if (tok >= NTOK) return;
#pragma unroll
  for (int k = 0; k < 2; ++k) {
    int e = topi[tok * 2 + k];
    unsigned pos = atomicAdd(&cursors[e], 1u);
    row_token[pos] = tok;
    row_p[pos] = topp[tok * 2 + k];
    topi[tok * 2 + k] = (int)pos;   // inverse map for combine
  }
}

// ---------------- aux loss ----------------
__global__ __launch_bounds__(256) void aux_kernel(const float* __restrict__ probs,
                                                  float* __restrict__ out_aux) {
  const int t = threadIdx.x;
  float a[8] = {0, 0, 0, 0, 0, 0, 0, 0};
  for (int tok = t; tok < NTOK; tok += 256) {
    const float4* p4 = (const float4*)(probs + (size_t)tok * 8);
    float4 lo = p4[0], hi = p4[1];
    a[0] += lo.x; a[1] += lo.y; a[2] += lo.z; a[3] += lo.w;
    a[4] += hi.x; a[5] += hi.y; a[6] += hi.z; a[7] += hi.w;
  }
  const int lane = t & 63, wave = t >> 6;
#pragma unroll
  for (int e = 0; e < 8; ++e)
    for (int o = 32; o > 0; o >>= 1) a[e] += __shfl_down(a[e], o);
  __shared__ float sh[4][8];
  if (lane == 0) {
#pragma unroll
    for (int e = 0; e < 8; ++e) sh[wave][e] = a[e];
  }
  __syncthreads();
  if (t == 0) {
    float aux = 0.f;
#pragma unroll
    for (int e = 0; e < 8; ++e) {
      float load = (sh[0][e] + sh[1][e] + sh[2][e] + sh[3][e]) * (1.f / NTOK);
      float d = load - 0.125f;
      aux += d * d;
    }
    out_aux[0] = aux;
  }
}

// ------- transpose + f32->bf16 cast: w[E][R][C] -> wt[E][C][R], 64x64 tiles -------
__global__ __launch_bounds__(256) void transpose_cast_kernel(
    const float* __restrict__ w, unsigned short* __restrict__ wt, int R, int C) {
  __shared__ float tile[64][65];
  const int e = blockIdx.z;
  const int c0 = blockIdx.x * 64, r0 = blockIdx.y * 64;
  const float* we = w + (size_t)e * R * C;
  unsigned short* wte = wt + (size_t)e * R * C;
  const int t = threadIdx.x;
  const int rr = t >> 4, cc = (t & 15) * 4;
#pragma unroll
  for (int i = 0; i < 4; ++i) {
    float4 v = *(const float4*)(we + (size_t)(r0 + rr + i * 16) * C + c0 + cc);
    tile[rr + i * 16][cc]     = v.x;
    tile[rr + i * 16][cc + 1] = v.y;
    tile[rr + i * 16][cc + 2] = v.z;
    tile[rr + i * 16][cc + 3] = v.w;
  }
  __syncthreads();
  const int col = t >> 4, r4 = (t & 15) * 4;
#pragma unroll
  for (int i = 0; i < 4; ++i) {
    int c = col + i * 16;
    ushort4 o;
    o.x = f2bf(tile[r4][c]);     o.y = f2bf(tile[r4 + 1][c]);
    o.z = f2bf(tile[r4 + 2][c]); o.w = f2bf(tile[r4 + 3][c]);
    *(ushort4*)(wte + (size_t)(c0 + c) * R + r0 + r4) = o;
  }
}

// ---------------- combine: out = x + y0[r] + y1[r] (both experts) ----------------
__global__ __launch_bounds__(256) void combine_kernel(
    const float* __restrict__ x, const unsigned short* __restrict__ y,
    const int* __restrict__ asn, float* __restrict__ out) {
  const int tok = blockIdx.x;
  const int t = threadIdx.x;
  const int r0 = asn[tok * 2], r1 = asn[tok * 2 + 1];
  float4 xv = *(const float4*)(x + (size_t)tok * DM + t * 4);
  const size_t HALF = (size_t)16384 * DM;
  ushort4 a0 = *(const ushort4*)(y + (size_t)r0 * DM + t * 4);
  ushort4 a1 = *(const ushort4*)(y + HALF + (size_t)r0 * DM + t * 4);
  ushort4 b0 = *(const ushort4*)(y + (size_t)r1 * DM + t * 4);
  ushort4 b1 = *(const ushort4*)(y + HALF + (size_t)r1 * DM + t * 4);
  float4 o;
  o.x = xv.x + bf2f(a0.x) + bf2f(a1.x) + bf2f(b0.x) + bf2f(b1.x);
  o.y = xv.y + bf2f(a0.y) + bf2f(a1.y) + bf2f(b0.y) + bf2f(b1.y);
  o.z = xv.z + bf2f(a0.z) + bf2f(a1.z) + bf2f(b0.z) + bf2f(b1.z);
  o.w = xv.w + bf2f(a0.w) + bf2f(a1.w) + bf2f(b0.w) + bf2f(b1.w);
  *(float4*)(out + (size_t)tok * DM + t * 4) = o;
}

// =====================================================================
// m97-structure GEMM: 128x128 tile, BK=64, 4 waves (2x2), single 32 KB
// LDS buffer, stage -> __syncthreads (vmcnt drain) -> 32 MFMA -> sync.
// Overlap comes from 3-4 resident blocks/CU (m114). XOR-swizzled LDS via
// pre-swizzled global source (rule #21). XCD-chunked item map, tile-major
// so col-blocks sharing an A-panel co-reside on one XCD's L2.
// =====================================================================

__device__ __forceinline__ void compute_ktile(const unsigned short* Ab,
                                              const unsigned short* Bb,
                                              int lane, int wr, int wc,
                                              f32x4 acc[4][4]) {
#pragma unroll
  for (int ks = 0; ks < 2; ++ks) {
    const int slot = ((ks * 4 + (lane >> 4)) ^ (lane & 7)) * 8;
    s16x8 af[4], bfr[4];
#pragma unroll
    for (int mf = 0; mf < 4; ++mf)
      af[mf] = *(const s16x8*)&Ab[(wr * 64 + mf * 16 + (lane & 15)) * 64 + slot];
#pragma unroll
    for (int nf = 0; nf < 4; ++nf)
      bfr[nf] = *(const s16x8*)&Bb[(wc * 64 + nf * 16 + (lane & 15)) * 64 + slot];
#pragma unroll
    for (int mf = 0; mf < 4; ++mf)
#pragma unroll
      for (int nf = 0; nf < 4; ++nf)
        acc[mf][nf] = __builtin_amdgcn_mfma_f32_16x16x32_bf16(af[mf], bfr[nf],
                                                              acc[mf][nf], 0, 0, 0);
  }
}

// ---------------- GEMM1: h = silu(xn[gather] @ w1 + b1), bf16 out ----------------
__global__ __launch_bounds__(256, 3) void gemm1_kernel(
    const unsigned short* __restrict__ xnb,   // [8192][1024]
    const unsigned short* __restrict__ w1t,   // [E][4096][1024]  ([n][k])
    const float* __restrict__ b1,             // [E][4096]
    const int* __restrict__ row_token,
    unsigned short* __restrict__ h,           // [16384][4096]
    const int4* __restrict__ tiles, const int* __restrict__ ntiles_p) {
  __shared__ unsigned short As[128 * 64];
  __shared__ unsigned short Bs[128 * 64];
  const int t = threadIdx.x, lane = t & 63, wave = t >> 6;
  const int wr = wave >> 1, wc = wave & 1;
  const int swz = ((t & 7) ^ ((t >> 3) & 7)) * 8;

  const int nItems = (*ntiles_p) << 5;            // 32 col-blocks per tile
  const int cs = (nItems + 7) >> 3;
  const int xcd = blockIdx.x & 7, lnx = blockIdx.x >> 3;
  const int wstep = (int)(gridDim.x >> 3);
  const int wend = ((xcd + 1) * cs < nItems) ? (xcd + 1) * cs : nItems;

  for (int w = xcd * cs + lnx; w < wend; w += wstep) {
    const int4 td = tiles[w >> 5];
    const int e = td.x, row_start = td.y, nrows = td.z;
    const int n0 = (w & 31) << 7;
    const unsigned short* Bw = w1t + (size_t)e * ((size_t)DF * DM);

    const unsigned short* asrc[4];
    const unsigned short* bsrc[4];
#pragma unroll
    for (int it = 0; it < 4; ++it) {
      int r = it * 32 + (t >> 3);
      int rc = r < nrows ? r : (nrows - 1);
      asrc[it] = xnb + (size_t)row_token[row_start + rc] * DM + swz;
      bsrc[it] = Bw + (size_t)(n0 + r) * DM + swz;
    }
    f32x4 acc[4][4];
#pragma unroll
    for (int i = 0; i < 4; ++i)
#pragma unroll
      for (int j = 0; j < 4; ++j) acc[i][j] = (f32x4){0.f, 0.f, 0.f, 0.f};

    for (int kt = 0; kt < DM / 64; ++kt) {
      const int k0 = kt * 64;
#pragma unroll
      for (int it = 0; it < 4; ++it) {
        gload_lds16(asrc[it] + k0, &As[it * 2048 + wave * 512]);
        gload_lds16(bsrc[it] + k0, &Bs[it * 2048 + wave * 512]);
      }
      __syncthreads();
      compute_ktile(As, Bs, lane, wr, wc, acc);
      __syncthreads();
    }

    const float* b1e = b1 + e * DF;
#pragma unroll
    for (int mf = 0; mf < 4; ++mf) {
      int rbase = wr * 64 + mf * 16 + ((lane >> 4) << 2);
#pragma unroll
      for (int nf = 0; nf < 4; ++nf) {
        int col = n0 + wc * 64 + nf * 16 + (lane & 15);
        float bias = b1e[col];
#pragma unroll
        for (int r = 0; r < 4; ++r) {
          int rl = rbase + r;
          if (rl < nrows) {
            float v = acc[mf][nf][r] + bias;
            float sv = v / (1.f + __expf(-v));
            h[(size_t)(row_start + rl) * DF + col] = f2bf(sv);
          }
        }
      }
    }
  }
}

// ------- GEMM2: y[kh][row] = p * (h @ w2[,khalf] + (kh==0)*b2), bf16 partials -------
__global__ __launch_bounds__(256, 3) void gemm2_kernel(
    const unsigned short* __restrict__ h,     // [16384][4096]
    const unsigned short* __restrict__ w2t,   // [E][1024][4096]  ([n][k])
    const float* __restrict__ b2,             // [E][1024]
    const int* __restrict__ row_p_dummy, const float* __restrict__ row_p,
    const int4* __restrict__ tiles, const int* __restrict__ ntiles_p,
    unsigned short* __restrict__ y) {          // [2][16384][1024]
  __shared__ unsigned short As[128 * 64];
  __shared__ unsigned short Bs[128 * 64];
  const int t = threadIdx.x, lane = t & 63, wave = t >> 6;
  const int wr = wave >> 1, wc = wave & 1;
  const int swz = ((t & 7) ^ ((t >> 3) & 7)) * 8;

  // item = (tile*8 + col)*2 + khalf  -> 16 items per tile, ~1056 total
  const int nItems = (*ntiles_p) << 4;
  const int cs = (nItems + 7) >> 3;
  const int xcd = blockIdx.x & 7, lnx = blockIdx.x >> 3;
  const int wstep = (int)(gridDim.x >> 3);
  const int wend = ((xcd + 1) * cs < nItems) ? (xcd + 1) * cs : nItems;

  for (int w = xcd * cs + lnx; w < wend; w += wstep) {
    const int4 td = tiles[w >> 4];
    const int e = td.x, row_start = td.y, nrows = td.z;
    const int n0 = ((w >> 1) & 7) << 7;
    const int kh = w & 1;
    const unsigned short* Bw = w2t + (size_t)e * ((size_t)DM * DF);

    const unsigned short* asrc[4];
    const unsigned short* bsrc[4];
#pragma unroll
    for (int it = 0; it < 4; ++it) {
      int r = it * 32 + (t >> 3);
      int rc = r < nrows ? r : (nrows - 1);
      asrc[it] = h + (size_t)(row_start + rc) * DF + swz;
      bsrc[it] = Bw + (size_t)(n0 + r) * DF + swz;
    }
    f32x4 acc[4][4];
#pragma unroll
    for (int i = 0; i < 4; ++i)
#pragma unroll
      for (int j = 0; j < 4; ++j) acc[i][j] = (f32x4){0.f, 0.f, 0.f, 0.f};

    const int kt0 = kh * 32;
    for (int kt = kt0; kt < kt0 + 32; ++kt) {
      const int k0 = kt * 64;
#pragma unroll
      for (int it = 0; it < 4; ++it) {
        gload_lds16(asrc[it] + k0, &As[it * 2048 + wave * 512]);
        gload_lds16(bsrc[it] + k0, &Bs[it * 2048 + wave * 512]);
      }
      __syncthreads();
      compute_ktile(As, Bs, lane, wr, wc, acc);
      __syncthreads();
    }

    const float* b2e = b2 + e * DM;
    unsigned short* yk = y + (size_t)kh * ((size_t)16384 * DM);
#pragma unroll
    for (int mf = 0; mf < 4; ++mf) {
      int rbase = wr * 64 + mf * 16 + ((lane >> 4) << 2);
      float prr[4]; int rok[4];
#pragma unroll
      for (int r = 0; r < 4; ++r) {
        int rl = rbase + r;
        rok[r] = rl < nrows;
        prr[r] = rok[r] ? row_p[row_start + rl] : 0.f;
      }
#pragma unroll
      for (int nf = 0; nf < 4; ++nf) {
        int col = n0 + wc * 64 + nf * 16 + (lane & 15);
        float bias = kh == 0 ? b2e[col] : 0.f;
#pragma unroll
        for (int r = 0; r < 4; ++r) {
          if (rok[r]) {
            float v = prr[r] * (acc[mf][nf][r] + bias);
            yk[(size_t)(row_start + rbase + r) * DM + col] = f2bf(v);
          }
        }
      }
    }
  }
}

// ---------------- launch ----------------
extern "C" void kernel_launch(void* const* d_in, const int* in_sizes, int n_in,
                              void* d_out, int out_size, void* d_ws, size_t ws_size,
                              hipStream_t stream) {
  const float* x     = (const float*)d_in[0];
  const float* gamma = (const float*)d_in[1];
  const float* beta  = (const float*)d_in[2];
  const float* rw    = (const float*)d_in[3];
  const float* rb    = (const float*)d_in[4];
  const float* w1    = (const float*)d_in[5];
  const float* b1    = (const float*)d_in[6];
  const float* w2    = (const float*)d_in[7];
  const float* b2    = (const float*)d_in[8];
  float* out = (float*)d_out;
  char* ws = (char*)d_ws;

  if (ws_size < WS_NEEDED) {
    sentinel_kernel<<<2048, 256, 0, stream>>>(out, out_size);
    return;
  }

  unsigned short* xnb = (unsigned short*)(ws + OFF_XN);
  unsigned short* w1t = (unsigned short*)(ws + OFF_W1T);
  unsigned short* y   = (unsigned short*)(ws + OFF_W1T);  // overlays w1t after gemm1
  unsigned short* w2t = (unsigned short*)(ws + OFF_W2T);
  unsigned short* h   = (unsigned short*)(ws + OFF_H);
  float* probs        = (float*)(ws + OFF_PROBS);
  int* topi           = (int*)(ws + OFF_TOPI);
  float* topp         = (float*)(ws + OFF_TOPP);
  int* row_token      = (int*)(ws + OFF_ROWTOK);
  float* row_p        = (float*)(ws + OFF_ROWP);
  unsigned* counts    = (unsigned*)(ws + OFF_COUNTS);
  unsigned* cursors   = (unsigned*)(ws + OFF_CURSORS);
  int* ntiles         = (int*)(ws + OFF_NTILES);
  int4* tiles         = (int4*)(ws + OFF_TILES);

  init_kernel<<<1, 64, 0, stream>>>(counts);
  ln_router_kernel<<<NTOK, 256, 0, stream>>>(x, gamma, beta, rw, rb, xnb, probs,
                                             topi, topp, counts);
  plan_kernel<<<1, 1, 0, stream>>>(counts, cursors, tiles, ntiles);
  scatter_kernel<<<NTOK / 256, 256, 0, stream>>>(topi, topp, cursors, row_token, row_p);
  aux_kernel<<<1, 256, 0, stream>>>(probs, out + (size_t)NTOK * DM);
  transpose_cast_kernel<<<dim3(DF / 64, DM / 64, NE), 256, 0, stream>>>(w1, w1t, DM, DF);
  transpose_cast_kernel<<<dim3(DM / 64, DF / 64, NE), 256, 0, stream>>>(w2, w2t, DF, DM);
  gemm1_kernel<<<1024, 256, 0, stream>>>(xnb, w1t, b1, row_token, h, tiles, ntiles);
  gemm2_kernel<<<1024, 256, 0, stream>>>(h, w2t, b2, topi, row_p, tiles, ntiles, y);
  combine_kernel<<<NTOK, 256, 0, stream>>>(x, y, topi, out);
}

// Round 6
// 806.452 us; speedup vs baseline: 1.4470x; 1.0558x over previous
//
#include <hip/hip_runtime.h>
#include <math.h>

#define NTOK 8192
#define DM 1024
#define NE 8
#define DF 4096
#define MAXTILES 136   // 128-row tiles: <=128 full + <=8 partial

typedef short  s16x8 __attribute__((ext_vector_type(8)));
typedef float  f32x4 __attribute__((ext_vector_type(4)));

// ---------------- workspace layout (bytes) ----------------
#define OFF_XN      0ull                       // 8192*1024*2        = 16777216
#define OFF_W1T     16777216ull                // 8*4096*1024*2      = 67108864  (y overlays after gemm1)
#define OFF_W2T     83886080ull                // 8*1024*4096*2      = 67108864
#define OFF_H       150994944ull               // 16384*4096*2       = 134217728
#define OFF_PROBS   285212672ull               // 8192*8*4           = 262144
#define OFF_TOPI    285474816ull               // 8192*2*4           = 65536 (becomes asn rows)
#define OFF_TOPP    285540352ull               // 8192*2*4           = 65536
#define OFF_ROWTOK  285605888ull               // 16384*4            = 65536
#define OFF_ROWP    285671424ull               // 16384*4            = 65536
#define OFF_COUNTS  285736960ull               // 8*4
#define OFF_CURSORS 285736992ull               // 8*4
#define OFF_NTILES  285737024ull               // 4 (+pad)
#define OFF_TILES   285737088ull               // 136*16 = 2176
#define WS_NEEDED   285739264ull

__device__ __forceinline__ unsigned short f2bf(float f) {
  unsigned u = __builtin_bit_cast(unsigned, f);
  u += 0x7fffu + ((u >> 16) & 1u);
  return (unsigned short)(u >> 16);
}
__device__ __forceinline__ float bf2f(unsigned short s) {
  unsigned u = ((unsigned)s) << 16;
  return __builtin_bit_cast(float, u);
}

__device__ __forceinline__ void gload_lds16(const void* g, void* l) {
  __builtin_amdgcn_global_load_lds(
      (const __attribute__((address_space(1))) void*)g,
      (__attribute__((address_space(3))) void*)l, 16, 0, 0);
}

// XCD-aware CHUNKED item range: split items 8 ways (one chunk per XCD, so
// same-A-panel items stay on one XCD's L2), then contiguous sub-chunks per
// block within the XCD (consecutive items share the A-panel -> L1/L2 hits).
__device__ __forceinline__ void chunk_range(int nItems, int* s, int* e) {
  const int xcd = blockIdx.x & 7, lnx = blockIdx.x >> 3;
  const int nbx = (int)(gridDim.x >> 3);
  const int cs = nItems >> 3, cr = nItems & 7;
  const int base = xcd * cs + (xcd < cr ? xcd : cr);
  const int csz  = cs + (xcd < cr ? 1 : 0);
  const int q = csz / nbx, r = csz % nbx;
  *s = base + lnx * q + (lnx < r ? lnx : r);
  *e = *s + q + (lnx < r ? 1 : 0);
}

// ---------------- init: zero expert counts ----------------
__global__ void init_kernel(unsigned* counts) {
  if (threadIdx.x < NE) counts[threadIdx.x] = 0u;
}

// ---------------- sentinel if ws too small ----------------
__global__ void sentinel_kernel(float* out, int n) {
  for (int i = blockIdx.x * 256 + threadIdx.x; i < n; i += 2048 * 256)
    out[i] = -12345.0f;
}

// ---------------- fused LayerNorm + router ----------------
__global__ __launch_bounds__(256) void ln_router_kernel(
    const float* __restrict__ x, const float* __restrict__ gamma,
    const float* __restrict__ beta, const float* __restrict__ rw,
    const float* __restrict__ rb, unsigned short* __restrict__ xnb,
    float* __restrict__ probs, int* __restrict__ topi,
    float* __restrict__ topp, unsigned* __restrict__ counts) {
  const int tok = blockIdx.x;
  const int t = threadIdx.x;
  const int lane = t & 63, wave = t >> 6;

  float4 xv = *(const float4*)(x + (size_t)tok * DM + t * 4);
  float s = xv.x + xv.y + xv.z + xv.w;
  float q = xv.x * xv.x + xv.y * xv.y + xv.z * xv.z + xv.w * xv.w;
  for (int o = 32; o > 0; o >>= 1) {
    s += __shfl_down(s, o);
    q += __shfl_down(q, o);
  }
  __shared__ float red[16];
  if (lane == 0) { red[wave] = s; red[8 + wave] = q; }
  __syncthreads();
  float tot  = red[0] + red[1] + red[2] + red[3];
  float totq = red[8] + red[9] + red[10] + red[11];
  float mu = tot * (1.0f / DM);
  float var = totq * (1.0f / DM) - mu * mu;
  float rstd = rsqrtf(var + 1e-5f);

  float4 g = *(const float4*)(gamma + t * 4);
  float4 b = *(const float4*)(beta + t * 4);
  float xn[4];
  xn[0] = (xv.x - mu) * rstd * g.x + b.x;
  xn[1] = (xv.y - mu) * rstd * g.y + b.y;
  xn[2] = (xv.z - mu) * rstd * g.z + b.z;
  xn[3] = (xv.w - mu) * rstd * g.w + b.w;
  ushort4 pk = { f2bf(xn[0]), f2bf(xn[1]), f2bf(xn[2]), f2bf(xn[3]) };
  *(ushort4*)(xnb + (size_t)tok * DM + t * 4) = pk;

  float a[8] = {0, 0, 0, 0, 0, 0, 0, 0};
  const float4* r4 = (const float4*)(rw + (size_t)t * 32);
#pragma unroll
  for (int j = 0; j < 4; ++j) {
    float4 lo = r4[j * 2], hi = r4[j * 2 + 1];
    a[0] += xn[j] * lo.x; a[1] += xn[j] * lo.y;
    a[2] += xn[j] * lo.z; a[3] += xn[j] * lo.w;
    a[4] += xn[j] * hi.x; a[5] += xn[j] * hi.y;
    a[6] += xn[j] * hi.z; a[7] += xn[j] * hi.w;
  }
#pragma unroll
  for (int e = 0; e < 8; ++e)
    for (int o = 32; o > 0; o >>= 1) a[e] += __shfl_down(a[e], o);
  __shared__ float lred[4][8];
  if (lane == 0) {
#pragma unroll
    for (int e = 0; e < 8; ++e) lred[wave][e] = a[e];
  }
  __syncthreads();
  if (t == 0) {
    float lg[8], mx = -1e30f;
#pragma unroll
    for (int e = 0; e < 8; ++e) {
      lg[e] = lred[0][e] + lred[1][e] + lred[2][e] + lred[3][e] + rb[e];
      mx = fmaxf(mx, lg[e]);
    }
    float ex[8], se = 0.f;
#pragma unroll
    for (int e = 0; e < 8; ++e) { ex[e] = expf(lg[e] - mx); se += ex[e]; }
    float inv = 1.f / se;
    float pr[8];
#pragma unroll
    for (int e = 0; e < 8; ++e) {
      pr[e] = ex[e] * inv;
      probs[tok * 8 + e] = pr[e];
    }
    int i0 = 0;
#pragma unroll
    for (int e = 1; e < 8; ++e) if (pr[e] > pr[i0]) i0 = e;
    int i1 = (i0 == 0) ? 1 : 0;
#pragma unroll
    for (int e = 0; e < 8; ++e)
      if (e != i0 && pr[e] > pr[i1]) i1 = e;
    float p0 = pr[i0], p1 = pr[i1], inv2 = 1.f / (p0 + p1);
    topi[tok * 2] = i0; topi[tok * 2 + 1] = i1;
    topp[tok * 2] = p0 * inv2; topp[tok * 2 + 1] = p1 * inv2;
    atomicAdd(&counts[i0], 1u);
    atomicAdd(&counts[i1], 1u);
  }
}

// ---------------- plan: offsets + 128-row tile descriptors ----------------
__global__ void plan_kernel(const unsigned* __restrict__ counts,
                            unsigned* __restrict__ cursors,
                            int4* __restrict__ tiles, int* __restrict__ ntiles) {
  if (threadIdx.x == 0 && blockIdx.x == 0) {
    unsigned o = 0; int nt = 0;
    for (int e = 0; e < NE; ++e) {
      cursors[e] = o;
      unsigned c = counts[e];
      for (unsigned st = 0; st < c; st += 128u) {
        unsigned nr = c - st; if (nr > 128u) nr = 128u;
        tiles[nt] = make_int4(e, (int)(o + st), (int)nr, 0);
        ++nt;
      }
      o += c;
    }
    *ntiles = nt;
  }
}

// ------- scatter: expert row lists + per-token assignment rows (into topi) -------
__global__ __launch_bounds__(256) void scatter_kernel(
    int* __restrict__ topi, const float* __restrict__ topp,
    unsigned* cursors, int* row_token, float* row_p) {
  int tok = blockIdx.x * 256 + threadIdx.x;
  if (tok >= NTOK) return;
#pragma unroll
  for (int k = 0; k < 2; ++k) {
    int e = topi[tok * 2 + k];
    unsigned pos = atomicAdd(&cursors[e], 1u);
    row_token[pos] = tok;
    row_p[pos] = topp[tok * 2 + k];
    topi[tok * 2 + k] = (int)pos;   // inverse map for combine
  }
}

// ---------------- aux loss ----------------
__global__ __launch_bounds__(256) void aux_kernel(const float* __restrict__ probs,
                                                  float* __restrict__ out_aux) {
  const int t = threadIdx.x;
  float a[8] = {0, 0, 0, 0, 0, 0, 0, 0};
  for (int tok = t; tok < NTOK; tok += 256) {
    const float4* p4 = (const float4*)(probs + (size_t)tok * 8);
    float4 lo = p4[0], hi = p4[1];
    a[0] += lo.x; a[1] += lo.y; a[2] += lo.z; a[3] += lo.w;
    a[4] += hi.x; a[5] += hi.y; a[6] += hi.z; a[7] += hi.w;
  }
  const int lane = t & 63, wave = t >> 6;
#pragma unroll
  for (int e = 0; e < 8; ++e)
    for (int o = 32; o > 0; o >>= 1) a[e] += __shfl_down(a[e], o);
  __shared__ float sh[4][8];
  if (lane == 0) {
#pragma unroll
    for (int e = 0; e < 8; ++e) sh[wave][e] = a[e];
  }
  __syncthreads();
  if (t == 0) {
    float aux = 0.f;
#pragma unroll
    for (int e = 0; e < 8; ++e) {
      float load = (sh[0][e] + sh[1][e] + sh[2][e] + sh[3][e]) * (1.f / NTOK);
      float d = load - 0.125f;
      aux += d * d;
    }
    out_aux[0] = aux;
  }
}

// ------- transpose + f32->bf16 cast: w[E][R][C] -> wt[E][C][R], 64x64 tiles -------
__global__ __launch_bounds__(256) void transpose_cast_kernel(
    const float* __restrict__ w, unsigned short* __restrict__ wt, int R, int C) {
  __shared__ float tile[64][65];
  const int e = blockIdx.z;
  const int c0 = blockIdx.x * 64, r0 = blockIdx.y * 64;
  const float* we = w + (size_t)e * R * C;
  unsigned short* wte = wt + (size_t)e * R * C;
  const int t = threadIdx.x;
  const int rr = t >> 4, cc = (t & 15) * 4;
#pragma unroll
  for (int i = 0; i < 4; ++i) {
    float4 v = *(const float4*)(we + (size_t)(r0 + rr + i * 16) * C + c0 + cc);
    tile[rr + i * 16][cc]     = v.x;
    tile[rr + i * 16][cc + 1] = v.y;
    tile[rr + i * 16][cc + 2] = v.z;
    tile[rr + i * 16][cc + 3] = v.w;
  }
  __syncthreads();
  const int col = t >> 4, r4 = (t & 15) * 4;
#pragma unroll
  for (int i = 0; i < 4; ++i) {
    int c = col + i * 16;
    ushort4 o;
    o.x = f2bf(tile[r4][c]);     o.y = f2bf(tile[r4 + 1][c]);
    o.z = f2bf(tile[r4 + 2][c]); o.w = f2bf(tile[r4 + 3][c]);
    *(ushort4*)(wte + (size_t)(c0 + c) * R + r0 + r4) = o;
  }
}

// ---------------- combine: out = x + y[kh0..1][r0] + y[kh0..1][r1] ----------------
__global__ __launch_bounds__(256) void combine_kernel(
    const float* __restrict__ x, const unsigned short* __restrict__ y,
    const int* __restrict__ asn, float* __restrict__ out) {
  const int tok = blockIdx.x;
  const int t = threadIdx.x;
  const int r0 = asn[tok * 2], r1 = asn[tok * 2 + 1];
  float4 xv = *(const float4*)(x + (size_t)tok * DM + t * 4);
  const size_t HALF = (size_t)16384 * DM;
  ushort4 a0 = *(const ushort4*)(y + (size_t)r0 * DM + t * 4);
  ushort4 a1 = *(const ushort4*)(y + HALF + (size_t)r0 * DM + t * 4);
  ushort4 b0 = *(const ushort4*)(y + (size_t)r1 * DM + t * 4);
  ushort4 b1 = *(const ushort4*)(y + HALF + (size_t)r1 * DM + t * 4);
  float4 o;
  o.x = xv.x + bf2f(a0.x) + bf2f(a1.x) + bf2f(b0.x) + bf2f(b1.x);
  o.y = xv.y + bf2f(a0.y) + bf2f(a1.y) + bf2f(b0.y) + bf2f(b1.y);
  o.z = xv.z + bf2f(a0.z) + bf2f(a1.z) + bf2f(b0.z) + bf2f(b1.z);
  o.w = xv.w + bf2f(a0.w) + bf2f(a1.w) + bf2f(b0.w) + bf2f(b1.w);
  *(float4*)(out + (size_t)tok * DM + t * 4) = o;
}

// =====================================================================
// m97-structure GEMMs: BK=64, 4 waves, single LDS buffer, 2 barriers per
// K-step; overlap via 4 resident blocks/CU (launch_bounds(256,4), grid
// 1024 = 4/CU). XOR-swizzled LDS via pre-swizzled global source (#21).
// Chunked XCD-aware item map (chunk_range) so same-A-panel items run
// back-to-back on one block / one XCD -> A re-reads hit L1/L2 not HBM.
// =====================================================================

// ---------------- GEMM1: h = silu(xn[gather] @ w1 + b1), 128x128 ----------------
__global__ __launch_bounds__(256, 4) void gemm1_kernel(
    const unsigned short* __restrict__ xnb,   // [8192][1024]
    const unsigned short* __restrict__ w1t,   // [E][4096][1024]  ([n][k])
    const float* __restrict__ b1,             // [E][4096]
    const int* __restrict__ row_token,
    unsigned short* __restrict__ h,           // [16384][4096]
    const int4* __restrict__ tiles, const int* __restrict__ ntiles_p) {
  __shared__ unsigned short As[128 * 64];
  __shared__ unsigned short Bs[128 * 64];
  const int t = threadIdx.x, lane = t & 63, wave = t >> 6;
  const int wr = wave >> 1, wc = wave & 1;
  const int swz = ((t & 7) ^ ((t >> 3) & 7)) * 8;

  int ws_, we_;
  chunk_range((*ntiles_p) << 5, &ws_, &we_);   // item = tile*32 + col

  for (int w = ws_; w < we_; ++w) {
    const int4 td = tiles[w >> 5];
    const int e = td.x, row_start = td.y, nrows = td.z;
    const int n0 = (w & 31) << 7;
    const unsigned short* Bw = w1t + (size_t)e * ((size_t)DF * DM);

    const unsigned short* asrc[4];
    const unsigned short* bsrc[4];
#pragma unroll
    for (int it = 0; it < 4; ++it) {
      int r = it * 32 + (t >> 3);
      int rc = r < nrows ? r : (nrows - 1);
      asrc[it] = xnb + (size_t)row_token[row_start + rc] * DM + swz;
      bsrc[it] = Bw + (size_t)(n0 + r) * DM + swz;
    }
    f32x4 acc[4][4];
#pragma unroll
    for (int i = 0; i < 4; ++i)
#pragma unroll
      for (int j = 0; j < 4; ++j) acc[i][j] = (f32x4){0.f, 0.f, 0.f, 0.f};

    for (int kt = 0; kt < DM / 64; ++kt) {
      const int k0 = kt * 64;
#pragma unroll
      for (int it = 0; it < 4; ++it) {
        gload_lds16(asrc[it] + k0, &As[it * 2048 + wave * 512]);
        gload_lds16(bsrc[it] + k0, &Bs[it * 2048 + wave * 512]);
      }
      __syncthreads();
#pragma unroll
      for (int ks = 0; ks < 2; ++ks) {
        const int slot = ((ks * 4 + (lane >> 4)) ^ (lane & 7)) * 8;
        s16x8 af[4], bfr[4];
#pragma unroll
        for (int mf = 0; mf < 4; ++mf)
          af[mf] = *(const s16x8*)&As[(wr * 64 + mf * 16 + (lane & 15)) * 64 + slot];
#pragma unroll
        for (int nf = 0; nf < 4; ++nf)
          bfr[nf] = *(const s16x8*)&Bs[(wc * 64 + nf * 16 + (lane & 15)) * 64 + slot];
#pragma unroll
        for (int mf = 0; mf < 4; ++mf)
#pragma unroll
          for (int nf = 0; nf < 4; ++nf)
            acc[mf][nf] = __builtin_amdgcn_mfma_f32_16x16x32_bf16(af[mf], bfr[nf],
                                                                  acc[mf][nf], 0, 0, 0);
      }
      __syncthreads();
    }

    const float* b1e = b1 + e * DF;
#pragma unroll
    for (int mf = 0; mf < 4; ++mf) {
      int rbase = wr * 64 + mf * 16 + ((lane >> 4) << 2);
#pragma unroll
      for (int nf = 0; nf < 4; ++nf) {
        int col = n0 + wc * 64 + nf * 16 + (lane & 15);
        float bias = b1e[col];
#pragma unroll
        for (int r = 0; r < 4; ++r) {
          int rl = rbase + r;
          if (rl < nrows) {
            float v = acc[mf][nf][r] + bias;
            float sv = v / (1.f + __expf(-v));
            h[(size_t)(row_start + rl) * DF + col] = f2bf(sv);
          }
        }
      }
    }
  }
}

// ------- GEMM2: y[kh][row] = p*(h @ w2[,kh] + (kh==0)*b2), 64x128, K-split 2 -------
__global__ __launch_bounds__(256, 4) void gemm2_kernel(
    const unsigned short* __restrict__ h,     // [16384][4096]
    const unsigned short* __restrict__ w2t,   // [E][1024][4096]  ([n][k])
    const float* __restrict__ b2,             // [E][1024]
    const float* __restrict__ row_p,
    const int4* __restrict__ tiles, const int* __restrict__ ntiles_p,
    unsigned short* __restrict__ y) {          // [2][16384][1024]
  __shared__ unsigned short As[64 * 64];
  __shared__ unsigned short Bs[128 * 64];
  const int t = threadIdx.x, lane = t & 63, wave = t >> 6;
  const int wr = wave >> 1, wc = wave & 1;
  const int swz = ((t & 7) ^ ((t >> 3) & 7)) * 8;

  int ws_, we_;
  chunk_range((*ntiles_p) << 5, &ws_, &we_);   // item = tile*32 + kh*16 + mh*8 + col

  for (int w = ws_; w < we_; ++w) {
    const int4 td = tiles[w >> 5];
    const int e = td.x, kh = (w >> 4) & 1, mh = (w >> 3) & 1;
    const int n0 = (w & 7) << 7;
    const int row_start = td.y + mh * 64;
    const int nrows_i = td.z - mh * 64;        // may be <=0 for tail tiles
    if (nrows_i <= 0) continue;
    const unsigned short* Bw = w2t + (size_t)e * ((size_t)DM * DF);

    const unsigned short* asrc[2];
    const unsigned short* bsrc[4];
#pragma unroll
    for (int it = 0; it < 2; ++it) {
      int r = it * 32 + (t >> 3);
      int rc = r < nrows_i ? r : (nrows_i - 1);
      asrc[it] = h + (size_t)(row_start + rc) * DF + swz;
    }
#pragma unroll
    for (int it = 0; it < 4; ++it) {
      int r = it * 32 + (t >> 3);
      bsrc[it] = Bw + (size_t)(n0 + r) * DF + swz;
    }
    f32x4 acc[2][4];
#pragma unroll
    for (int i = 0; i < 2; ++i)
#pragma unroll
      for (int j = 0; j < 4; ++j) acc[i][j] = (f32x4){0.f, 0.f, 0.f, 0.f};

    const int ktEnd = kh * 32 + 32;
    for (int kt = kh * 32; kt < ktEnd; ++kt) {
      const int k0 = kt * 64;
#pragma unroll
      for (int it = 0; it < 2; ++it)
        gload_lds16(asrc[it] + k0, &As[it * 2048 + wave * 512]);
#pragma unroll
      for (int it = 0; it < 4; ++it)
        gload_lds16(bsrc[it] + k0, &Bs[it * 2048 + wave * 512]);
      __syncthreads();
#pragma unroll
      for (int ks = 0; ks < 2; ++ks) {
        const int slot = ((ks * 4 + (lane >> 4)) ^ (lane & 7)) * 8;
        s16x8 af[2], bfr[4];
#pragma unroll
        for (int mf = 0; mf < 2; ++mf)
          af[mf] = *(const s16x8*)&As[(wr * 32 + mf * 16 + (lane & 15)) * 64 + slot];
#pragma unroll
        for (int nf = 0; nf < 4; ++nf)
          bfr[nf] = *(const s16x8*)&Bs[(wc * 64 + nf * 16 + (lane & 15)) * 64 + slot];
#pragma unroll
        for (int mf = 0; mf < 2; ++mf)
#pragma unroll
          for (int nf = 0; nf < 4; ++nf)
            acc[mf][nf] = __builtin_amdgcn_mfma_f32_16x16x32_bf16(af[mf], bfr[nf],
                                                                  acc[mf][nf], 0, 0, 0);
      }
      __syncthreads();
    }

    const float* b2e = b2 + e * DM;
    unsigned short* yk = y + (size_t)kh * ((size_t)16384 * DM);
#pragma unroll
    for (int mf = 0; mf < 2; ++mf) {
      int rbase = wr * 32 + mf * 16 + ((lane >> 4) << 2);
      float prr[4]; int rok[4];
#pragma unroll
      for (int r = 0; r < 4; ++r) {
        int rl = rbase + r;
        rok[r] = rl < nrows_i;
        prr[r] = rok[r] ? row_p[row_start + rl] : 0.f;
      }
#pragma unroll
      for (int nf = 0; nf < 4; ++nf) {
        int col = n0 + wc * 64 + nf * 16 + (lane & 15);
        float bias = kh == 0 ? b2e[col] : 0.f;
#pragma unroll
        for (int r = 0; r < 4; ++r) {
          if (rok[r]) {
            float v = prr[r] * (acc[mf][nf][r] + bias);
            yk[(size_t)(row_start + rbase + r) * DM + col] = f2bf(v);
          }
        }
      }
    }
  }
}

// ---------------- launch ----------------
extern "C" void kernel_launch(void* const* d_in, const int* in_sizes, int n_in,
                              void* d_out, int out_size, void* d_ws, size_t ws_size,
                              hipStream_t stream) {
  const float* x     = (const float*)d_in[0];
  const float* gamma = (const float*)d_in[1];
  const float* beta  = (const float*)d_in[2];
  const float* rw    = (const float*)d_in[3];
  const float* rb    = (const float*)d_in[4];
  const float* w1    = (const float*)d_in[5];
  const float* b1    = (const float*)d_in[6];
  const float* w2    = (const float*)d_in[7];
  const float* b2    = (const float*)d_in[8];
  float* out = (float*)d_out;
  char* ws = (char*)d_ws;

  if (ws_size < WS_NEEDED) {
    sentinel_kernel<<<2048, 256, 0, stream>>>(out, out_size);
    return;
  }

  unsigned short* xnb = (unsigned short*)(ws + OFF_XN);
  unsigned short* w1t = (unsigned short*)(ws + OFF_W1T);
  unsigned short* y   = (unsigned short*)(ws + OFF_W1T);  // overlays w1t after gemm1
  unsigned short* w2t = (unsigned short*)(ws + OFF_W2T);
  unsigned short* h   = (unsigned short*)(ws + OFF_H);
  float* probs        = (float*)(ws + OFF_PROBS);
  int* topi           = (int*)(ws + OFF_TOPI);
  float* topp         = (float*)(ws + OFF_TOPP);
  int* row_token      = (int*)(ws + OFF_ROWTOK);
  float* row_p        = (float*)(ws + OFF_ROWP);
  unsigned* counts    = (unsigned*)(ws + OFF_COUNTS);
  unsigned* cursors   = (unsigned*)(ws + OFF_CURSORS);
  int* ntiles         = (int*)(ws + OFF_NTILES);
  int4* tiles         = (int4*)(ws + OFF_TILES);

  init_kernel<<<1, 64, 0, stream>>>(counts);
  ln_router_kernel<<<NTOK, 256, 0, stream>>>(x, gamma, beta, rw, rb, xnb, probs,
                                             topi, topp, counts);
  plan_kernel<<<1, 1, 0, stream>>>(counts, cursors, tiles, ntiles);
  scatter_kernel<<<NTOK / 256, 256, 0, stream>>>(topi, topp, cursors, row_token, row_p);
  aux_kernel<<<1, 256, 0, stream>>>(probs, out + (size_t)NTOK * DM);
  transpose_cast_kernel<<<dim3(DF / 64, DM / 64, NE), 256, 0, stream>>>(w1, w1t, DM, DF);
  transpose_cast_kernel<<<dim3(DM / 64, DF / 64, NE), 256, 0, stream>>>(w2, w2t, DF, DM);
  gemm1_kernel<<<1024, 256, 0, stream>>>(xnb, w1t, b1, row_token, h, tiles, ntiles);
  gemm2_kernel<<<1024, 256, 0, stream>>>(h, w2t, b2, row_p, tiles, ntiles, y);
  combine_kernel<<<NTOK, 256, 0, stream>>>(x, y, topi, out);
}